// Round 9
// baseline (829.242 us; speedup 1.0000x reference)
//
#include <hip/hip_runtime.h>
#include <stdint.h>

// SAN1d: 4x { y = conv_same(x,w); a = topk_abs(y,k); out += conv_same(a,w) }
// B=64 rows, L=262144, ks={65,33,17,9}, k=L//ks.
//
// R9 (profile-driven): R8's k1 was KS-independent (78us both passes) -> the
// 8x per-block {stage,flush,barrier(vmcnt0)} cadence governed, not FMA.
// Now: whole 8K chunk staged ONCE per block (global_load_lds, 33KB LDS),
// ONE barrier, then conv+store free-running (4 outputs/thread x 8 groups,
// float4 stores, aligned b128 window reads). k5 same structure, mask-on-stage,
// 32 reg accs across both kernel-groups. k2_hist atomic-free (8 private
// partial hists/rk, merged in findbin which also zeroes ccount -> no memsets).

#define B_ 64
#define L_ 262144
#define NBINS 8192      // |y| bits >> 18
#define CAPC 8192       // candidate cap per (row,kernel)
#define LCAP 1024       // per-block local candidate cap (k3)
#define CH 8192         // per-block output chunk
#define XSTG 8448       // staged floats: CH+64 halo, rounded to 33*256
#define NCH 32          // L_/CH
#define NH 8            // partial-hist blocks per rk
#define NSCAN 16        // k3 scan blocks per rk

typedef unsigned int u32;

__device__ const int d_K[4] = {4032, 7943, 15420, 29127};  // L_ // ks

// ---------------------------------------------------------------- stage x/y
__device__ __forceinline__ void stage_x(const float* __restrict__ xr, int c0,
                                        float* dst, int tid)
{
  const bool interior = (c0 >= 32) && (c0 - 32 + XSTG <= L_);
  if (interior) {
    const float* g0 = xr + (c0 - 32);
    const int wv = tid >> 6, lane = tid & 63;
#pragma unroll
    for (int r = 0; r < 9; ++r) {
      const int idx = r * 4 + wv;                // wave-uniform chunk index
      if (idx < XSTG / 256) {
        const int off = idx * 256;               // floats
        __builtin_amdgcn_global_load_lds(
            (const __attribute__((address_space(1))) unsigned int*)(const void*)(g0 + off + lane * 4),
            (__attribute__((address_space(3))) unsigned int*)(void*)(dst + off),
            16, 0, 0);
      }
    }
  } else {
    for (int i = tid; i < XSTG; i += 256) {
      const int g = c0 - 32 + i;
      dst[i] = (g >= 0 && g < L_) ? xr[g] : 0.0f;  // SAME zero-pad as real taps
    }
  }
}

// ---------------------------------------------------------------- conv core
// 4 outputs/thread x 8 groups (stride 1024). j-ascending fmaf chain per output
// (bit-identical to all previous rounds). Window reads are aligned float4.
template<int KS>
__device__ __forceinline__ void conv_acc(const float* __restrict__ w,
                                         const float* xb, float a[32], int tid)
{
  constexpr int PAD = KS / 2;
  constexpr int NW = (KS + 3) / 4;               // KS==1 mod 4 -> exact
  float wreg[KS];
#pragma unroll
  for (int j = 0; j < KS; ++j) wreg[j] = w[j];   // uniform -> SGPRs
#pragma unroll
  for (int s = 0; s < 8; ++s) {
    const int o = s * 1024 + tid * 4;
    const float4* lp = (const float4*)(xb + o + 32 - PAD);   // 16B-aligned
    float a0 = a[s*4], a1 = a[s*4+1], a2 = a[s*4+2], a3 = a[s*4+3];
#pragma unroll
    for (int c = 0; c < NW; ++c) {
      float4 xq = lp[c];
#pragma unroll
      for (int e = 0; e < 4; ++e) {
        const int p = 4 * c + e;
        const float xv = (e==0) ? xq.x : (e==1) ? xq.y : (e==2) ? xq.z : xq.w;
        if (p     < KS)            a0 = fmaf(xv, wreg[p],     a0);
        if (p-1 >= 0 && p-1 < KS)  a1 = fmaf(xv, wreg[p-1],   a1);
        if (p-2 >= 0 && p-2 < KS)  a2 = fmaf(xv, wreg[p-2],   a2);
        if (p-3 >= 0 && p-3 < KS)  a3 = fmaf(xv, wreg[p-3],   a3);
      }
    }
    a[s*4] = a0; a[s*4+1] = a1; a[s*4+2] = a2; a[s*4+3] = a3;
  }
}

// ---------------------------------------------------------------- K1
__global__ __launch_bounds__(256) void k1_conv(
    const float* __restrict__ x, const float* __restrict__ w0,
    const float* __restrict__ w1, const float* __restrict__ w2,
    const float* __restrict__ w3, float* __restrict__ y,
    int kk0, int ng)
{
  __shared__ __align__(16) float xb[XSTG];       // 33 KB
  const int tid = threadIdx.x;
  const int kg = blockIdx.y;
  const int row = blockIdx.z;
  const int rkl = row * ng + kg;
  const int kk = kk0 + kg;
  const int c0 = blockIdx.x * CH;
  const float* xr = x + (size_t)row * L_;
  float* yrow = y + (size_t)rkl * L_;

  stage_x(xr, c0, xb, tid);
  __syncthreads();                                // the ONLY barrier

  float a[32];
#pragma unroll
  for (int i = 0; i < 32; ++i) a[i] = 0.0f;
  switch (kk) {
    case 0:  conv_acc<65>(w0, xb, a, tid); break;
    case 1:  conv_acc<33>(w1, xb, a, tid); break;
    case 2:  conv_acc<17>(w2, xb, a, tid); break;
    default: conv_acc< 9>(w3, xb, a, tid); break;
  }
#pragma unroll
  for (int s = 0; s < 8; ++s)
    *(float4*)&yrow[c0 + s * 1024 + tid * 4] =
        make_float4(a[s*4], a[s*4+1], a[s*4+2], a[s*4+3]);
}

// ---------------------------------------------------------------- K2a: partial hists (atomic-free global)
__global__ __launch_bounds__(256) void k2_hist(
    const float* __restrict__ y, u32* __restrict__ phist, int ng)
{
  __shared__ u32 h32[NBINS / 2];                 // 16 KB packed u16
  const int tid = threadIdx.x;
  const int rkl = blockIdx.z * ng + blockIdx.y;
  for (int i = tid; i < NBINS / 2; i += 256) h32[i] = 0u;
  __syncthreads();
  const float4* src = (const float4*)(y + (size_t)rkl * L_ + blockIdx.x * (L_ / NH));
  for (int i = tid; i < (L_ / NH) / 4; i += 256) {
    float4 v = src[i];
    const float* vf = (const float*)&v;
#pragma unroll
    for (int c = 0; c < 4; ++c) {
      u32 bin = (__float_as_uint(vf[c]) & 0x7fffffffu) >> 18;
      atomicAdd(&h32[bin >> 1], 1u << (16 * (bin & 1)));   // 32768/block < u16 max
    }
  }
  __syncthreads();
  u32* dst = phist + ((size_t)rkl * NH + blockIdx.x) * (NBINS / 2);
  for (int i = tid; i < NBINS / 2; i += 256) dst[i] = h32[i];   // plain stores
}

// ---------------------------------------------------------------- K2b: merge + bin find (+ ccount zero)
__global__ __launch_bounds__(256) void k2_findbin(
    const u32* __restrict__ phist, u32* __restrict__ bbin, u32* __restrict__ rrem,
    u32* __restrict__ ccount, int kk0, int ng)
{
  __shared__ u32 h[NBINS];
  __shared__ u32 ssum[256];
  const int tid = threadIdx.x;
  const int rkl = blockIdx.x;
  const u32 k = (u32)d_K[kk0 + (rkl % ng)];
  for (int i = tid; i < NBINS / 2; i += 256) {
    u32 lo = 0, hi = 0;
#pragma unroll
    for (int b = 0; b < NH; ++b) {
      u32 v = phist[((size_t)rkl * NH + b) * (NBINS / 2) + i];
      lo += v & 0xffffu; hi += v >> 16;
    }
    h[2 * i] = lo; h[2 * i + 1] = hi;
  }
  __syncthreads();
  u32 s = 0;
  for (int i = 0; i < 32; ++i) s += h[tid * 32 + i];
  ssum[tid] = s;
  __syncthreads();
  if (tid == 0) {
    u32 cum = 0; int b = 0;
    for (int t = 255; t >= 0; --t) {             // walk from the top (largest |y|)
      if (cum + ssum[t] >= k) {
        for (int i = t * 32 + 31; i >= t * 32; --i) {
          if (cum + h[i] >= k) { b = i; break; }
          cum += h[i];
        }
        break;
      }
      cum += ssum[t];
    }
    bbin[rkl] = (u32)b;
    rrem[rkl] = k - cum;                         // 1-based rank inside bin b
    ccount[rkl] = 0u;                            // reset for k3 (replaces memset)
  }
}

// ---------------------------------------------------------------- K3: scan y
__global__ __launch_bounds__(256) void k3_scan(
    const float* __restrict__ y, const u32* __restrict__ bbin,
    u32* __restrict__ ccount, uint2* __restrict__ cand, int ng)
{
  __shared__ uint2 lcand[LCAP];
  __shared__ u32 lmeta[3];
  const int tid = threadIdx.x;
  const int rkl = blockIdx.z * ng + blockIdx.y;
  const u32 target = bbin[rkl];
  if (tid == 0) lmeta[0] = 0u;
  __syncthreads();
  const float* yr = y + (size_t)rkl * L_;
  const int c0 = blockIdx.x * (L_ / NSCAN);
  const float4* src = (const float4*)(yr + c0);
  for (int i = tid; i < (L_ / NSCAN) / 4; i += 256) {
    float4 v = src[i];
    const float* vf = (const float*)&v;
#pragma unroll
    for (int c = 0; c < 4; ++c) {
      u32 ab = __float_as_uint(vf[c]) & 0x7fffffffu;
      if ((ab >> 18) == target) {
        u32 slot = atomicAdd(&lmeta[0], 1u);
        if (slot < LCAP) lcand[slot] = make_uint2(ab, (u32)(c0 + 4 * i + c));
      }
    }
  }
  __syncthreads();
  if (tid == 0) {
    u32 m = lmeta[0]; if (m > LCAP) m = LCAP;
    lmeta[1] = m;
    lmeta[2] = atomicAdd(&ccount[rkl], m);
  }
  __syncthreads();
  const u32 m = lmeta[1], bse = lmeta[2];
  uint2* cd = cand + (size_t)rkl * CAPC;
  for (u32 i = tid; i < m; i += 256)
    if (bse + i < CAPC) cd[bse + i] = lcand[i];
}

// ---------------------------------------------------------------- K4: select
__global__ __launch_bounds__(256) void k4_select(
    const uint2* __restrict__ cand, const u32* __restrict__ ccount,
    const u32* __restrict__ bbinA, const u32* __restrict__ rremA,
    u32* __restrict__ thr, u32* __restrict__ keepAll,
    u32* __restrict__ excN, u32* __restrict__ excL)
{
  __shared__ u32 cab[CAPC];
  __shared__ u32 h64[64];
  __shared__ u32 sh[3];
  __shared__ u32 lidx[64];
  __shared__ u32 lcnt;
  const int rkl = blockIdx.x;
  int n = (int)min(ccount[rkl], (u32)CAPC);
  u32 r = rremA[rkl];
  if (r > (u32)n) r = (u32)n;                    // overflow fallback
  const uint2* cd = cand + (size_t)rkl * CAPC;
  for (int i = threadIdx.x; i < n; i += 256) cab[i] = cd[i].x & 0x3ffffu;

  u32 sel = 0;
  for (int round = 0; round < 3; ++round) {      // 3 x 6-bit MSD radix select
    const int shift = 12 - 6 * round;
    const u32 himask = (round == 0) ? 0u : ((0x3ffffu << (shift + 6)) & 0x3ffffu);
    if (threadIdx.x < 64) h64[threadIdx.x] = 0u;
    __syncthreads();
    for (int i = threadIdx.x; i < n; i += 256) {
      u32 v = cab[i];
      if ((v & himask) == (sel & himask)) atomicAdd(&h64[(v >> shift) & 63u], 1u);
    }
    __syncthreads();
    if (threadIdx.x == 0) {
      u32 cum = 0; int d = 0;
      for (int dd = 63; dd >= 0; --dd) {
        if (cum + h64[dd] >= r) { d = dd; break; }
        cum += h64[dd];
      }
      sh[0] = (u32)d;
      sh[1] = r - cum;
      sh[2] = h64[d];
    }
    __syncthreads();
    sel |= sh[0] << shift;
    r = sh[1];
  }
  const u32 dup = sh[2];
  const u32 m = r;
  if (threadIdx.x == 0) thr[rkl] = (bbinA[rkl] << 18) | sel;

  if (m >= dup) {
    if (threadIdx.x == 0) { keepAll[rkl] = 1u; excN[rkl] = 0u; }
    return;
  }
  if (threadIdx.x == 0) lcnt = 0u;
  __syncthreads();
  for (int i = threadIdx.x; i < n; i += 256) {
    if (cab[i] == sel) {
      u32 s2 = atomicAdd(&lcnt, 1u);
      if (s2 < 64) lidx[s2] = cd[i].y;
    }
  }
  __syncthreads();
  if (threadIdx.x == 0) {
    int c = (int)min(lcnt, 64u);
    for (int i = 1; i < c; ++i) {                // sort asc (top_k tie-break)
      u32 v = lidx[i]; int j = i - 1;
      while (j >= 0 && lidx[j] > v) { lidx[j + 1] = lidx[j]; --j; }
      lidx[j + 1] = v;
    }
    u32 mm = min(m, 32u);
    keepAll[rkl] = 0u; excN[rkl] = mm;
    for (u32 i = 0; i < mm; ++i) excL[(size_t)rkl * 32 + i] = lidx[i];
  }
}

// ---------------------------------------------------------------- K5: final
__device__ __forceinline__ float k5_mask(float yv, int g, u32 t_ab, u32 ka,
                                         u32 en, const u32* __restrict__ excp)
{
  u32 ab = __float_as_uint(yv) & 0x7fffffffu;
  bool keep = ab > t_ab;
  if (ab == t_ab) {                              // exact top_k tie semantics
    if (ka) keep = true;
    else {
      for (u32 e = 0; e < en; ++e)
        if (excp[e] == (u32)g) { keep = true; break; }
    }
  }
  return keep ? yv : 0.0f;
}

__global__ __launch_bounds__(256) void k5_final(
    const float* __restrict__ y, const float* __restrict__ w0,
    const float* __restrict__ w1, const float* __restrict__ w2,
    const float* __restrict__ w3, const u32* __restrict__ thr,
    const u32* __restrict__ keepAll, const u32* __restrict__ excN,
    const u32* __restrict__ excL, float* __restrict__ out,
    int kk0, int ng)
{
  __shared__ __align__(16) float xb[XSTG];
  const int tid = threadIdx.x;
  const int row = blockIdx.y;
  const int c0 = blockIdx.x * CH;
  float a[32];
#pragma unroll
  for (int i = 0; i < 32; ++i) a[i] = 0.0f;

  for (int kg = 0; kg < ng; ++kg) {
    if (kg) __syncthreads();                     // prior conv reads done
    const int rkl = row * ng + kg;
    const int kk = kk0 + kg;
    const u32 t_ab = thr[rkl], ka = keepAll[rkl], en = excN[rkl];
    const u32* excp = excL + (size_t)rkl * 32;
    const float* yr = y + (size_t)rkl * L_;
    // stage masked y on [c0-32, c0+CH+32)
    const bool interior = (c0 >= 32) && (c0 - 32 + CH + 64 <= L_);
    if (interior) {
      const float4* src = (const float4*)(yr + c0 - 32);
      for (int i = tid; i < (CH + 64) / 4; i += 256) {
        float4 v = src[i];
        float* vf = (float*)&v;
        const int gb = c0 - 32 + 4 * i;
#pragma unroll
        for (int c = 0; c < 4; ++c) vf[c] = k5_mask(vf[c], gb + c, t_ab, ka, en, excp);
        ((float4*)xb)[i] = v;
      }
    } else {
      for (int i = tid; i < CH + 64; i += 256) {
        const int g = c0 - 32 + i;
        xb[i] = (g >= 0 && g < L_) ? k5_mask(yr[g], g, t_ab, ka, en, excp) : 0.0f;
      }
    }
    __syncthreads();
    switch (kk) {
      case 0:  conv_acc<65>(w0, xb, a, tid); break;
      case 1:  conv_acc<33>(w1, xb, a, tid); break;
      case 2:  conv_acc<17>(w2, xb, a, tid); break;
      default: conv_acc< 9>(w3, xb, a, tid); break;
    }
  }

  float* orow = out + (size_t)row * L_ + c0;
  if (kk0 == 0) {
#pragma unroll
    for (int s = 0; s < 8; ++s)
      *(float4*)&orow[s * 1024 + tid * 4] =
          make_float4(a[s*4], a[s*4+1], a[s*4+2], a[s*4+3]);
  } else {
#pragma unroll
    for (int s = 0; s < 8; ++s) {
      float4 p = *(const float4*)&orow[s * 1024 + tid * 4];
      p.x += a[s*4]; p.y += a[s*4+1]; p.z += a[s*4+2]; p.w += a[s*4+3];
      *(float4*)&orow[s * 1024 + tid * 4] = p;
    }
  }
}

// ---------------------------------------------------------------- host
extern "C" void kernel_launch(void* const* d_in, const int* in_sizes, int n_in,
                              void* d_out, int out_size, void* d_ws, size_t ws_size,
                              hipStream_t stream)
{
  (void)in_sizes; (void)n_in; (void)out_size;
  const float* x  = (const float*)d_in[0];
  const float* w0 = (const float*)d_in[1];
  const float* w1 = (const float*)d_in[2];
  const float* w2 = (const float*)d_in[3];
  const float* w3 = (const float*)d_in[4];
  float* out = (float*)d_out;

  // per-rk ws: y(L) + phist(NH*NBINS/2) + 6 scalars + excL(32) + cand(CAPC)
  auto need = [](int ng) -> size_t {
    return (size_t)ng * 64 * ((size_t)L_ * 4 + NH * (NBINS / 2) * 4 + 6 * 4 + 32 * 4 + CAPC * 8);
  };
  int ng = 1;
  if (ws_size >= need(4)) ng = 4;
  else if (ws_size >= need(2)) ng = 2;

  const size_t NRK = (size_t)64 * ng;
  float* y     = (float*)d_ws;
  u32* phist   = (u32*)(y + NRK * L_);
  u32* ccount  = phist + NRK * NH * (NBINS / 2);
  u32* bbin    = ccount + NRK;
  u32* rrem    = bbin + NRK;
  u32* thr     = rrem + NRK;
  u32* kAll    = thr + NRK;
  u32* excN    = kAll + NRK;
  u32* excL    = excN + NRK;               // NRK*32
  uint2* cand  = (uint2*)(excL + NRK * 32);

  for (int kk0 = 0; kk0 < 4; kk0 += ng) {
    dim3 g1(NCH, ng, B_);
    k1_conv<<<g1, 256, 0, stream>>>(x, w0, w1, w2, w3, y, kk0, ng);
    dim3 gh(NH, ng, B_);
    k2_hist<<<gh, 256, 0, stream>>>(y, phist, ng);
    k2_findbin<<<(int)NRK, 256, 0, stream>>>(phist, bbin, rrem, ccount, kk0, ng);
    dim3 g3(NSCAN, ng, B_);
    k3_scan<<<g3, 256, 0, stream>>>(y, bbin, ccount, cand, ng);
    k4_select<<<(int)NRK, 256, 0, stream>>>(cand, ccount, bbin, rrem, thr, kAll, excN, excL);
    dim3 g5(NCH, B_);
    k5_final<<<g5, 256, 0, stream>>>(y, w0, w1, w2, w3, thr, kAll, excN, excL, out, kk0, ng);
  }
}

// Round 10
// 426.233 us; speedup vs baseline: 1.9455x; 1.9455x over previous
//
#include <hip/hip_runtime.h>
#include <stdint.h>

// SAN1d: 4x { y = conv_same(x,w); a = topk_abs(y,k); out += conv_same(a,w) }
// B=64 rows, L=262144, ks={65,33,17,9}, k=L//ks.
//
// R10: R9's 4-outputs/thread float4 LDS windows caused 40.8M bank-conflict
// cycles (16B lane stride -> 8-way). Revert k1/k5 to the R8 proven bodies
// (stride-9 scalar windows, ybuf flush-under-conv, one barrier/subtile;
// 0 conflicts, k1=78us). New: histogram fused back into k1 from acc regs at
// NBINS=4096 (8KB LDS, k1 stays 3 blocks/CU) -> k2_hist kernel deleted
// (saves a full 134MB y re-read per pass). k4 radix widened to 19 bits.

#define B_ 64
#define L_ 262144
#define NBINS 4096      // |y| bits >> 19  (12 bits)
#define CAPC 8192       // candidate cap per (row,kernel); expected max ~6k
#define LCAP 1024       // per-block local candidate cap (k3)
#define TSUB 2304       // 256 threads * 9 outputs
#define SUBS 8          // subtiles per K1 block
#define NCHUNK 15       // ceil(L / (TSUB*SUBS))
#define XSTG 2560       // staged x tile incl. halo + gload granularity pad
#define T5 2304         // K5 tile
#define NT5 114         // ceil(L / T5)
#define NSCAN 16        // k3 scan blocks per rk; L/NSCAN = 16384

typedef unsigned int u32;

__device__ const int d_K[4] = {4032, 7943, 15420, 29127};  // L_ // ks

// ---------------------------------------------------------------- K1 staging
// Interior: async global->LDS, 16B/lane, wave-uniform LDS base (+lane*16 by HW).
// Pad region [2368,2560) may hold garbage row data; conv never reads it.
__device__ __forceinline__ void k1_stage(const float* __restrict__ xr, int base,
                                         float* dst, int tid)
{
  const bool interior = (base >= 32) && (base - 32 + XSTG <= L_);
  if (interior) {
    const float* g0 = xr + (base - 32);
    const int wv = tid >> 6, lane = tid & 63;
#pragma unroll
    for (int r = 0; r < 3; ++r) {
      const int off = (r * 4 + wv) * 256;          // floats; wave-uniform
      if (off < XSTG) {
        __builtin_amdgcn_global_load_lds(
            (const __attribute__((address_space(1))) unsigned int*)(const void*)(g0 + off + lane * 4),
            (__attribute__((address_space(3))) unsigned int*)(void*)(dst + off),
            16, 0, 0);
      }
    }
  } else {
    for (int i = tid; i < TSUB + 64; i += 256) {
      const int g = base - 32 + i;
      dst[i] = (g >= 0 && g < L_) ? xr[g] : 0.0f;  // SAME zero-pad as real taps
    }
  }
}

// ---------------------------------------------------------------- K1 body
template<int KS>
__device__ __forceinline__ void k1_body(
    const float* __restrict__ xr, const float* __restrict__ w,
    float* __restrict__ yrow, u32* __restrict__ gh,
    float* xb0, float* xb1, float* yb0, float* yb1, u32* h32)
{
  constexpr int PAD = KS / 2;
  constexpr int OFF = 32 - PAD;            // staged tile origin is base-32
  const int tid = threadIdx.x;

  float wreg[KS];
#pragma unroll
  for (int j = 0; j < KS; ++j) wreg[j] = w[j];

  for (int i = tid; i < NBINS / 2; i += 256) h32[i] = 0u;

  const int base0 = blockIdx.x * SUBS * TSUB;
  k1_stage(xr, base0, xb0, tid);
  __syncthreads();                          // stage0 + h32 zero complete

  int pendBase = -1;
  float* pendBuf = nullptr;

  for (int it = 0; it < SUBS; ++it) {
    const int base = base0 + it * TSUB;
    if (base >= L_) break;                  // uniform across block
    float* xcur = (it & 1) ? xb1 : xb0;
    float* xnxt = (it & 1) ? xb0 : xb1;
    float* ycur = (it & 1) ? yb1 : yb0;
    const int nbase = base + TSUB;
    if (it + 1 < SUBS && nbase < L_)
      k1_stage(xr, nbase, xnxt, tid);       // async; completes under conv

    // ---- flush previous subtile's y: coalesced float4 (hidden under conv)
    if (pendBase >= 0) {
      const int n4 = min(TSUB, L_ - pendBase) >> 2;
      float4* dst = (float4*)(yrow + pendBase);
      for (int i = tid; i < n4; i += 256) dst[i] = ((const float4*)pendBuf)[i];
    }

    // ---- conv: 9 outputs/thread, j-ascending fmaf chain (bit-stable)
    float acc[9];
#pragma unroll
    for (int r = 0; r < 9; ++r) acc[r] = 0.0f;
    const int q0 = tid * 9;                 // stride 9 (coprime 32) -> bank-clean
#pragma unroll
    for (int p = 0; p < KS + 8; ++p) {      // sliding window: p = r + j
      float xv = xcur[q0 + OFF + p];
#pragma unroll
      for (int r = 0; r < 9; ++r) {
        const int j = p - r;
        if (j >= 0 && j < KS) acc[r] = fmaf(xv, wreg[j], acc[r]);
      }
    }

    // ---- y -> LDS ybuf (stride-9 writes, bank-clean)
#pragma unroll
    for (int r = 0; r < 9; ++r) ycur[q0 + r] = acc[r];

    // ---- histogram from regs (packed u16 pairs; block total 18432 < 65536)
    const int g0 = base + q0;
#pragma unroll
    for (int r = 0; r < 9; ++r) {
      if (g0 + r < L_) {
        u32 bin = (__float_as_uint(acc[r]) & 0x7fffffffu) >> 19;
        atomicAdd(&h32[bin >> 1], 1u << (16 * (bin & 1)));
      }
    }

    pendBase = base; pendBuf = ycur;
    __syncthreads();  // single barrier: xnxt staged, ycur visible, flush done
  }

  // ---- epilogue flush
  if (pendBase >= 0) {
    const int n4 = min(TSUB, L_ - pendBase) >> 2;
    float4* dst = (float4*)(yrow + pendBase);
    for (int i = tid; i < n4; i += 256) dst[i] = ((const float4*)pendBuf)[i];
  }

  // ---- merge histogram (skip-zero device atomics; <=4096 per block)
  for (int i = tid; i < NBINS / 2; i += 256) {
    u32 v = h32[i];
    u32 lo = v & 0xffffu, hi = v >> 16;
    if (lo) atomicAdd(&gh[2 * i], lo);
    if (hi) atomicAdd(&gh[2 * i + 1], hi);
  }
}

__global__ __launch_bounds__(256) void k1_conv(
    const float* __restrict__ x, const float* __restrict__ w0,
    const float* __restrict__ w1, const float* __restrict__ w2,
    const float* __restrict__ w3, float* __restrict__ y,
    u32* __restrict__ ghist, int kk0, int ng)
{
  __shared__ __align__(16) float xb[2][XSTG];     // 20 KB x double-buffer
  __shared__ __align__(16) float yb[2][TSUB];     // 18 KB y double-buffer
  __shared__ u32 h32[NBINS / 2];                  // 8 KB packed u16 hist
  const int kg = blockIdx.y;
  const int row = blockIdx.z;
  const int rkl = row * ng + kg;
  const int kk = kk0 + kg;
  const float* xr = x + (size_t)row * L_;
  float* yrow = y + (size_t)rkl * L_;
  u32* gh = ghist + (size_t)rkl * NBINS;
  switch (kk) {
    case 0:  k1_body<65>(xr, w0, yrow, gh, xb[0], xb[1], yb[0], yb[1], h32); break;
    case 1:  k1_body<33>(xr, w1, yrow, gh, xb[0], xb[1], yb[0], yb[1], h32); break;
    case 2:  k1_body<17>(xr, w2, yrow, gh, xb[0], xb[1], yb[0], yb[1], h32); break;
    default: k1_body< 9>(xr, w3, yrow, gh, xb[0], xb[1], yb[0], yb[1], h32); break;
  }
}

// ---------------------------------------------------------------- K2: bin find (+ ccount zero)
__global__ __launch_bounds__(256) void k2_findbin(
    const u32* __restrict__ ghist, u32* __restrict__ bbin, u32* __restrict__ rrem,
    u32* __restrict__ ccount, int kk0, int ng)
{
  __shared__ u32 h[NBINS];
  __shared__ u32 ssum[256];
  const int tid = threadIdx.x;
  const int rkl = blockIdx.x;
  const u32 k = (u32)d_K[kk0 + (rkl % ng)];
  const u32* gh = ghist + (size_t)rkl * NBINS;
  for (int i = tid; i < NBINS; i += 256) h[i] = gh[i];
  __syncthreads();
  u32 s = 0;
  for (int i = 0; i < 16; ++i) s += h[tid * 16 + i];
  ssum[tid] = s;
  __syncthreads();
  if (tid == 0) {
    u32 cum = 0; int b = 0;
    for (int t = 255; t >= 0; --t) {       // walk from the top (largest |y|)
      if (cum + ssum[t] >= k) {
        for (int i = t * 16 + 15; i >= t * 16; --i) {
          if (cum + h[i] >= k) { b = i; break; }
          cum += h[i];
        }
        break;
      }
      cum += ssum[t];
    }
    bbin[rkl] = (u32)b;
    rrem[rkl] = k - cum;                   // 1-based rank inside bin b
    ccount[rkl] = 0u;                      // reset for k3 (replaces memset)
  }
}

// ---------------------------------------------------------------- K3: scan y
__global__ __launch_bounds__(256) void k3_scan(
    const float* __restrict__ y, const u32* __restrict__ bbin,
    u32* __restrict__ ccount, uint2* __restrict__ cand, int ng)
{
  __shared__ uint2 lcand[LCAP];
  __shared__ u32 lmeta[3];
  const int tid = threadIdx.x;
  const int rkl = blockIdx.z * ng + blockIdx.y;
  const u32 target = bbin[rkl];
  if (tid == 0) lmeta[0] = 0u;
  __syncthreads();
  const float* yr = y + (size_t)rkl * L_;
  const int c0 = blockIdx.x * (L_ / NSCAN);
  const float4* src = (const float4*)(yr + c0);
  for (int i = tid; i < (L_ / NSCAN) / 4; i += 256) {
    float4 v = src[i];
    const float* vf = (const float*)&v;
#pragma unroll
    for (int c = 0; c < 4; ++c) {
      u32 ab = __float_as_uint(vf[c]) & 0x7fffffffu;
      if ((ab >> 19) == target) {
        u32 slot = atomicAdd(&lmeta[0], 1u);
        if (slot < LCAP) lcand[slot] = make_uint2(ab, (u32)(c0 + 4 * i + c));
      }
    }
  }
  __syncthreads();
  if (tid == 0) {
    u32 m = lmeta[0]; if (m > LCAP) m = LCAP;
    lmeta[1] = m;
    lmeta[2] = atomicAdd(&ccount[rkl], m);
  }
  __syncthreads();
  const u32 m = lmeta[1], bse = lmeta[2];
  uint2* cd = cand + (size_t)rkl * CAPC;
  for (u32 i = tid; i < m; i += 256)
    if (bse + i < CAPC) cd[bse + i] = lcand[i];
}

// ---------------------------------------------------------------- K4: select (19-bit: 7+6+6)
__global__ __launch_bounds__(256) void k4_select(
    const uint2* __restrict__ cand, const u32* __restrict__ ccount,
    const u32* __restrict__ bbinA, const u32* __restrict__ rremA,
    u32* __restrict__ thr, u32* __restrict__ keepAll,
    u32* __restrict__ excN, u32* __restrict__ excL)
{
  __shared__ u32 cab[CAPC];
  __shared__ u32 h128[128];
  __shared__ u32 sh[3];
  __shared__ u32 lidx[64];
  __shared__ u32 lcnt;
  const int rkl = blockIdx.x;
  int n = (int)min(ccount[rkl], (u32)CAPC);
  u32 r = rremA[rkl];
  if (r > (u32)n) r = (u32)n;                    // overflow fallback
  const uint2* cd = cand + (size_t)rkl * CAPC;
  for (int i = threadIdx.x; i < n; i += 256) cab[i] = cd[i].x & 0x7ffffu;

  u32 sel = 0;
#pragma unroll
  for (int round = 0; round < 3; ++round) {
    const int shift = (round == 0) ? 12 : (round == 1) ? 6 : 0;
    const int width = (round == 0) ? 7 : 6;
    const int hb = shift + width;                // known-bits boundary
    const int nb = 1 << width;
    if (threadIdx.x < nb) h128[threadIdx.x] = 0u;
    __syncthreads();
    for (int i = threadIdx.x; i < n; i += 256) {
      u32 v = cab[i];
      if ((v >> hb) == (sel >> hb))
        atomicAdd(&h128[(v >> shift) & (u32)(nb - 1)], 1u);
    }
    __syncthreads();
    if (threadIdx.x == 0) {
      u32 cum = 0; int d = 0;
      for (int dd = nb - 1; dd >= 0; --dd) {
        if (cum + h128[dd] >= r) { d = dd; break; }
        cum += h128[dd];
      }
      sh[0] = (u32)d;
      sh[1] = r - cum;
      sh[2] = h128[d];
    }
    __syncthreads();
    sel |= sh[0] << shift;
    r = sh[1];
  }
  const u32 dup = sh[2];                   // multiplicity of threshold value
  const u32 m = r;                         // how many tied values to keep
  if (threadIdx.x == 0) thr[rkl] = (bbinA[rkl] << 19) | sel;

  if (m >= dup) {
    if (threadIdx.x == 0) { keepAll[rkl] = 1u; excN[rkl] = 0u; }
    return;
  }
  if (threadIdx.x == 0) lcnt = 0u;
  __syncthreads();
  for (int i = threadIdx.x; i < n; i += 256) {
    if (cab[i] == sel) {
      u32 s2 = atomicAdd(&lcnt, 1u);
      if (s2 < 64) lidx[s2] = cd[i].y;
    }
  }
  __syncthreads();
  if (threadIdx.x == 0) {
    int c = (int)min(lcnt, 64u);
    for (int i = 1; i < c; ++i) {          // sort asc (top_k tie-break)
      u32 v = lidx[i]; int j = i - 1;
      while (j >= 0 && lidx[j] > v) { lidx[j + 1] = lidx[j]; --j; }
      lidx[j + 1] = v;
    }
    u32 mm = min(m, 32u);
    keepAll[rkl] = 0u; excN[rkl] = mm;
    for (u32 i = 0; i < mm; ++i) excL[(size_t)rkl * 32 + i] = lidx[i];
  }
}

// ---------------------------------------------------------------- K5: final
__device__ __forceinline__ float k5_mask(float yv, int g, u32 t_ab, u32 ka,
                                         u32 en, const u32* __restrict__ excp)
{
  u32 ab = __float_as_uint(yv) & 0x7fffffffu;
  bool keep = ab > t_ab;
  if (ab == t_ab) {                        // exact top_k tie semantics
    if (ka) keep = true;
    else {
      for (u32 e = 0; e < en; ++e)
        if (excp[e] == (u32)g) { keep = true; break; }
    }
  }
  return keep ? yv : 0.0f;
}

template<int KS>
__device__ __forceinline__ void k5_conv(
    const float* __restrict__ w, const float* abuf, float* accO)
{
  constexpr int PAD = KS / 2;
  constexpr int OFF2 = 32 - PAD;
  float wreg[KS];
#pragma unroll
  for (int j = 0; j < KS; ++j) wreg[j] = w[j];
  const int o0 = threadIdx.x * 9;
#pragma unroll
  for (int p = 0; p < KS + 8; ++p) {
    float av = abuf[o0 + OFF2 + p];
#pragma unroll
    for (int r = 0; r < 9; ++r) {
      const int j = p - r;
      if (j >= 0 && j < KS) accO[r] = fmaf(av, wreg[j], accO[r]);
    }
  }
}

__global__ __launch_bounds__(256) void k5_final(
    const float* __restrict__ y, const float* __restrict__ w0,
    const float* __restrict__ w1, const float* __restrict__ w2,
    const float* __restrict__ w3, const u32* __restrict__ thr,
    const u32* __restrict__ keepAll, const u32* __restrict__ excN,
    const u32* __restrict__ excL, float* __restrict__ out,
    int kk0, int ng)
{
  __shared__ __align__(16) float abuf[T5 + 64];
  const int tid = threadIdx.x;
  const int row = blockIdx.y;
  const int tile0 = blockIdx.x * T5;
  float accO[9];
#pragma unroll
  for (int r = 0; r < 9; ++r) accO[r] = 0.0f;

  for (int kg = 0; kg < ng; ++kg) {
    const int rkl = row * ng + kg;
    const int kk = kk0 + kg;
    const u32 t_ab = thr[rkl], ka = keepAll[rkl], en = excN[rkl];
    const u32* excp = excL + (size_t)rkl * 32;
    const float* yr = y + (size_t)rkl * L_;
    // stage masked y on [tile0-32, tile0+T5+32)
    const bool interior = (tile0 >= 32) && (tile0 + T5 + 32 <= L_);
    if (interior) {
      const float4* src = (const float4*)(yr + tile0 - 32);
      for (int i = tid; i < (T5 + 64) / 4; i += 256) {
        float4 v = src[i];
        float* vf = (float*)&v;
#pragma unroll
        for (int c = 0; c < 4; ++c)
          vf[c] = k5_mask(vf[c], tile0 - 32 + 4 * i + c, t_ab, ka, en, excp);
        ((float4*)abuf)[i] = v;
      }
    } else {
      for (int i = tid; i < T5 + 64; i += 256) {
        int g = tile0 - 32 + i;
        float av = 0.0f;
        if (g >= 0 && g < L_) av = k5_mask(yr[g], g, t_ab, ka, en, excp);
        abuf[i] = av;
      }
    }
    __syncthreads();
    switch (kk) {
      case 0:  k5_conv<65>(w0, abuf, accO); break;
      case 1:  k5_conv<33>(w1, abuf, accO); break;
      case 2:  k5_conv<17>(w2, abuf, accO); break;
      default: k5_conv< 9>(w3, abuf, accO); break;
    }
    __syncthreads();                       // abuf reused by next kg
  }

  // LDS transpose -> coalesced float4 out write (RMW on later passes)
  const int o0 = tid * 9;
#pragma unroll
  for (int r = 0; r < 9; ++r) abuf[o0 + r] = accO[r];
  __syncthreads();
  float* orow = out + (size_t)row * L_ + tile0;
  const int n4 = min(T5, L_ - tile0) / 4;
  if (kk0 == 0) {
    for (int i = tid; i < n4; i += 256)
      ((float4*)orow)[i] = ((const float4*)abuf)[i];
  } else {
    for (int i = tid; i < n4; i += 256) {
      float4 p = ((const float4*)orow)[i];
      float4 a = ((const float4*)abuf)[i];
      p.x += a.x; p.y += a.y; p.z += a.z; p.w += a.w;
      ((float4*)orow)[i] = p;
    }
  }
}

// ---------------------------------------------------------------- host
extern "C" void kernel_launch(void* const* d_in, const int* in_sizes, int n_in,
                              void* d_out, int out_size, void* d_ws, size_t ws_size,
                              hipStream_t stream)
{
  (void)in_sizes; (void)n_in; (void)out_size;
  const float* x  = (const float*)d_in[0];
  const float* w0 = (const float*)d_in[1];
  const float* w1 = (const float*)d_in[2];
  const float* w2 = (const float*)d_in[3];
  const float* w3 = (const float*)d_in[4];
  float* out = (float*)d_out;

  // per-rk ws: y(L) + ghist(NBINS) + 6 scalars + excL(32) + cand(CAPC)
  auto need = [](int ng) -> size_t {
    return (size_t)ng * 64 * ((size_t)L_ * 4 + NBINS * 4 + 6 * 4 + 32 * 4 + CAPC * 8);
  };
  int ng = 1;
  if (ws_size >= need(4)) ng = 4;
  else if (ws_size >= need(2)) ng = 2;

  const size_t NRK = (size_t)64 * ng;
  float* y     = (float*)d_ws;
  u32* ghist   = (u32*)(y + NRK * L_);
  u32* ccount  = ghist + NRK * NBINS;
  u32* bbin    = ccount + NRK;
  u32* rrem    = bbin + NRK;
  u32* thr     = rrem + NRK;
  u32* kAll    = thr + NRK;
  u32* excN    = kAll + NRK;
  u32* excL    = excN + NRK;               // NRK*32
  uint2* cand  = (uint2*)(excL + NRK * 32);

  for (int kk0 = 0; kk0 < 4; kk0 += ng) {
    hipMemsetAsync(ghist, 0, NRK * NBINS * sizeof(u32), stream);
    dim3 g1(NCHUNK, ng, B_);
    k1_conv<<<g1, 256, 0, stream>>>(x, w0, w1, w2, w3, y, ghist, kk0, ng);
    k2_findbin<<<(int)NRK, 256, 0, stream>>>(ghist, bbin, rrem, ccount, kk0, ng);
    dim3 g3(NSCAN, ng, B_);
    k3_scan<<<g3, 256, 0, stream>>>(y, bbin, ccount, cand, ng);
    k4_select<<<(int)NRK, 256, 0, stream>>>(cand, ccount, bbin, rrem, thr, kAll, excN, excL);
    dim3 g5(NT5, B_);
    k5_final<<<g5, 256, 0, stream>>>(y, w0, w1, w2, w3, thr, kAll, excN, excL, out, kk0, ng);
  }
}